// Round 4
// baseline (432.003 us; speedup 1.0000x reference)
//
#include <hip/hip_runtime.h>
#include <math.h>

namespace {

constexpr int Hh = 384;
constexpr int Ww = 384;
constexpr int Bb = 4;
constexpr int HW = Hh * Ww;          // 147456
constexpr int NPIX = Bb * HW;        // 589824
constexpr int ITERS = 20;
constexpr int TPB = 256;
constexpr int NBLK = NPIX / (TPB * 4);       // 576 blocks, 4 px/thread
constexpr int BLKS_PER_B = NBLK / Bb;        // 144

__device__ __forceinline__ float fsub_rn_(float a, float b) {
    return __fadd_rn(a, -b);
}

// 9 pairwise weights for pixel (h,w) of batch-slice fmb = feature_map[b] ([3,HW])
__device__ __forceinline__ void compute_weights(const float* __restrict__ fmb,
                                                int h, int w, int hw,
                                                float* __restrict__ wgt) {
    float c0 = __fadd_rn(fmb[0 * HW + hw], 10.0f);
    float c1 = __fadd_rn(fmb[1 * HW + hw], 10.0f);
    float c2 = __fadd_rn(fmb[2 * HW + hw], 10.0f);
#pragma unroll
    for (int ki = 0; ki < 3; ++ki) {
#pragma unroll
        for (int kj = 0; kj < 3; ++kj) {
            const int k = ki * 3 + kj;
            const int hh = h + ki - 1;
            const int ww2 = w + kj - 1;
            if (hh < 0 || hh >= Hh || ww2 < 0 || ww2 >= Ww) {
                wgt[k] = 0.0f;
            } else {
                const int nhw = hh * Ww + ww2;
                float d0 = fsub_rn_(__fadd_rn(fmb[0 * HW + nhw], 10.0f), c0);
                float d1 = fsub_rn_(__fadd_rn(fmb[1 * HW + nhw], 10.0f), c1);
                float d2 = fsub_rn_(__fadd_rn(fmb[2 * HW + nhw], 10.0f), c2);
                float ss = __fadd_rn(__fadd_rn(__fmul_rn(d0, d0), __fmul_rn(d1, d1)),
                                     __fmul_rn(d2, d2));
                float color = __fdiv_rn(-ss, 0.5f);                 // /(2*0.5^2)
                const float spk = __fdiv_rn(
                    (float)((ki - 1) * (ki - 1) + (kj - 1) * (kj - 1)), 1800.0f);
                wgt[k] = __fmul_rn(3.0f, expf(fsub_rn_(color, spk)));
            }
        }
    }
}

// Device-scope grid barrier. arrive: 16 counters padded to 64B; epoch: 1 int.
// Monotonic: barrier idx's target is NBLK*(idx+1); counters zeroed per launch
// by a hipMemsetAsync captured in the graph. `last`: non-master blocks don't
// wait (no further work), master does no epoch release.
__device__ __forceinline__ void grid_barrier(int* arrive, int* epoch, int idx,
                                             bool last) {
    __syncthreads();   // all block's loads/stores drained (vmcnt(0) before s_barrier)
    if (threadIdx.x == 0)
        __hip_atomic_fetch_add(&arrive[(blockIdx.x & 15) << 4], 1,
                               __ATOMIC_RELEASE, __HIP_MEMORY_SCOPE_AGENT);
    if (blockIdx.x == 0) {
        if (threadIdx.x < 64) {
            const int target = NBLK * (idx + 1);
            for (;;) {
                int v = 0;
                if (threadIdx.x < 16)
                    v = __hip_atomic_load(&arrive[threadIdx.x << 4],
                                          __ATOMIC_RELAXED, __HIP_MEMORY_SCOPE_AGENT);
#pragma unroll
                for (int off = 1; off < 64; off <<= 1) v += __shfl_xor(v, off, 64);
                if (v >= target) break;
                __builtin_amdgcn_s_sleep(2);
            }
            __builtin_amdgcn_fence(__ATOMIC_ACQUIRE, "agent");
            if (threadIdx.x == 0 && !last)
                __hip_atomic_store(epoch, idx + 1, __ATOMIC_RELEASE,
                                   __HIP_MEMORY_SCOPE_AGENT);
        }
    } else if (!last) {
        if (threadIdx.x == 0) {
            while (__hip_atomic_load(epoch, __ATOMIC_RELAXED,
                                     __HIP_MEMORY_SCOPE_AGENT) < idx + 1)
                __builtin_amdgcn_s_sleep(2);
            __builtin_amdgcn_fence(__ATOMIC_ACQUIRE, "agent");
        }
    }
    __syncthreads();
}

// state byte: bit0 = (channel0 == 0.55f), bit1 = (channel1 == 0.55f)
__global__ __launch_bounds__(TPB, 4) void fused_kernel(
        const float* __restrict__ x, const float* __restrict__ t,
        const float* __restrict__ fm, float* __restrict__ out,
        int* __restrict__ arrive, int* __restrict__ epoch,
        int* __restrict__ partial,
        unsigned char* __restrict__ st0, unsigned char* __restrict__ st1) {
    const int tid4 = blockIdx.x * TPB + threadIdx.x;
    const int p = tid4 * 4;
    const int b = p / HW, hw = p - b * HW;
    const int h = hw / Ww, w0 = hw - h * Ww;

    const float Lg45 = (float)(-log((double)0.45f));
    const float Lg55 = (float)(-log((double)0.55f));

    // ---- once: weights + targets into registers, init state ----
    const float* fmb = fm + (size_t)b * 3 * HW;
    float wall[9][4];
#pragma unroll
    for (int j = 0; j < 4; ++j) {
        float wgt[9];
        compute_weights(fmb, h, w0 + j, hw + j, wgt);
#pragma unroll
        for (int k = 0; k < 9; ++k) wall[k][j] = wgt[k];
    }
    float4 xv = reinterpret_cast<const float4*>(x)[tid4];
    float4 tv = reinterpret_cast<const float4*>(t)[tid4];
    const float tj[4] = {tv.x, tv.y, tv.z, tv.w};
    uchar4 s4;
    s4.x = (__fmul_rn(xv.x, tv.x) > 0.5f) ? 2 : 1;
    s4.y = (__fmul_rn(xv.y, tv.y) > 0.5f) ? 2 : 1;
    s4.z = (__fmul_rn(xv.z, tv.z) > 0.5f) ? 2 : 1;
    s4.w = (__fmul_rn(xv.w, tv.w) > 0.5f) ? 2 : 1;
    *reinterpret_cast<uchar4*>(st0 + p) = s4;

    grid_barrier(arrive, epoch, 0, false);

    // ---- 20 iterations, ping-pong state, one barrier each ----
    unsigned char* cur = st0;
    unsigned char* nxt = st1;
    for (int it = 0; it < ITERS; ++it) {
        const bool fin = (it == ITERS - 1);
        const unsigned char* sb = cur + (size_t)b * HW;
        unsigned char ns4[4];
        float o4[4];
#pragma unroll
        for (int j = 0; j < 4; ++j) {
            const int w = w0 + j;
            float a0 = 0.0f, a1 = 0.0f;
#pragma unroll
            for (int ki = 0; ki < 3; ++ki) {
                const int hh = h + ki - 1;
                if (hh < 0 || hh >= Hh) continue;
                const unsigned char* row = sb + hh * Ww;
#pragma unroll
                for (int kj = 0; kj < 3; ++kj) {
                    const int ww2 = w + kj - 1;
                    if (ww2 < 0 || ww2 >= Ww) continue;
                    const int k = ki * 3 + kj;
                    unsigned char s = row[ww2];
                    float u0 = (s & 1) ? Lg55 : Lg45;
                    float u1 = (s & 2) ? Lg55 : Lg45;
                    a0 = __fadd_rn(a0, __fmul_rn(u0, wall[k][j]));
                    a1 = __fadd_rn(a1, __fmul_rn(u1, wall[k][j]));
                }
            }
            float f0 = expf(-a0);
            float f1 = __fmul_rn(expf(-a1), tj[j]);
            f0 = __fadd_rn(f0, 1e-6f);
            f1 = __fadd_rn(f1, 1e-6f);
            float S = __fadd_rn(f0, f1);
            float f1n = __fdiv_rn(f1, S);
            if (fin) {
                o4[j] = (f1n > 0.5f) ? 1.0f : 0.0f;
            } else {
                float f0n = __fdiv_rn(f0, S);
                ns4[j] = (unsigned char)((f0n > 0.5f ? 1 : 0) | (f1n > 0.5f ? 2 : 0));
            }
        }
        if (fin) {
            reinterpret_cast<float4*>(out)[tid4] =
                make_float4(o4[0], o4[1], o4[2], o4[3]);
            int cnt = (o4[0] != 0.0f) + (o4[1] != 0.0f) +
                      (o4[2] != 0.0f) + (o4[3] != 0.0f);
            const int lane = threadIdx.x & 63;
            const int wv = threadIdx.x >> 6;
#pragma unroll
            for (int off = 32; off; off >>= 1) cnt += __shfl_down(cnt, off, 64);
            __shared__ int sred[4];
            if (lane == 0) sred[wv] = cnt;
            __syncthreads();
            if (threadIdx.x == 0)
                partial[blockIdx.x] = sred[0] + sred[1] + sred[2] + sred[3];
        } else {
            *reinterpret_cast<uchar4*>(nxt + p) =
                make_uchar4(ns4[0], ns4[1], ns4[2], ns4[3]);
        }
        grid_barrier(arrive, epoch, it + 1, fin);
        unsigned char* tmp = cur; cur = nxt; nxt = tmp;
    }

    // ---- block 0: reduce partials -> valid ----
    if (blockIdx.x == 0) {
        const int wv = threadIdx.x >> 6;      // batch 0..3
        const int lane = threadIdx.x & 63;
        const int base = wv * BLKS_PER_B;     // 144 partials per batch = 64+64+16
        int s = partial[base + lane] + partial[base + 64 + lane];
        if (lane < 16) s += partial[base + 128 + lane];
#pragma unroll
        for (int off = 32; off; off >>= 1) s += __shfl_down(s, off, 64);
        if (lane == 0) {
            float cf = (float)s;
            const float lo = (float)(147456.0 * 0.05);
            const float hi = (float)(147456.0 * 0.95);
            out[NPIX + wv] = (cf >= lo && cf <= hi) ? 1.0f : 0.0f;
        }
    }
}

}  // namespace

extern "C" void kernel_launch(void* const* d_in, const int* in_sizes, int n_in,
                              void* d_out, int out_size, void* d_ws, size_t ws_size,
                              hipStream_t stream) {
    const float* x  = (const float*)d_in[0];
    const float* tg = (const float*)d_in[1];
    const float* fm = (const float*)d_in[2];
    float* out = (float*)d_out;

    char* ws = (char*)d_ws;
    // layout: [arrive 16x64B = 1024][epoch 4 .. pad to 2048][partial 2304 .. pad to 8192][st0][st1]
    int* arrive = (int*)ws;
    int* epoch  = (int*)(ws + 1024);
    int* partial = (int*)(ws + 2048);
    unsigned char* st0 = (unsigned char*)(ws + 8192);
    unsigned char* st1 = st0 + NPIX;

    // zero barrier state (arrive counters + epoch) every call — graph-captured
    (void)hipMemsetAsync(ws, 0, 1040, stream);

    fused_kernel<<<NBLK, TPB, 0, stream>>>(x, tg, fm, out, arrive, epoch,
                                           partial, st0, st1);
}

// Round 5
// 119.963 us; speedup vs baseline: 3.6011x; 3.6011x over previous
//
#include <hip/hip_runtime.h>
#include <math.h>

namespace {

constexpr int Hh = 384;
constexpr int Ww = 384;
constexpr int Bb = 4;
constexpr int HW = Hh * Ww;          // 147456
constexpr int NPIX = Bb * HW;        // 589824
constexpr int ITERS = 20;
constexpr int TPB = 256;

// 2D tiling: each block owns a 128x8 tile (4 px/thread), 3x48 tiles/batch
constexpr int TILE_W = 128;
constexpr int TILE_H = 8;
constexpr int TX = Ww / TILE_W;              // 3
constexpr int TY = Hh / TILE_H;              // 48
constexpr int BLKS_PER_B = TX * TY;          // 144
constexpr int NBLK = Bb * BLKS_PER_B;        // 576

// halo region staged in LDS per iteration: rows row0-1..row0+8, cols col0-4..col0+131
constexpr int RROWS = TILE_H + 2;            // 10
constexpr int RCOLSB = TILE_W + 8;           // 136 bytes
constexpr int RDW = RCOLSB / 4;              // 34 dwords/row
constexpr int RTOT = RROWS * RDW;            // 340 dwords

__device__ __forceinline__ float fsub_rn_(float a, float b) {
    return __fadd_rn(a, -b);
}

__device__ __forceinline__ unsigned ld_agent_u32(const void* p) {
    return __hip_atomic_load((const unsigned*)p, __ATOMIC_RELAXED,
                             __HIP_MEMORY_SCOPE_AGENT);
}
__device__ __forceinline__ void st_agent_u32(void* p, unsigned v) {
    __hip_atomic_store((unsigned*)p, v, __ATOMIC_RELAXED,
                       __HIP_MEMORY_SCOPE_AGENT);
}
__device__ __forceinline__ int ld_agent_i32(const int* p) {
    return __hip_atomic_load(p, __ATOMIC_RELAXED, __HIP_MEMORY_SCOPE_AGENT);
}

// 9 pairwise weights for pixel (h,w) of batch-slice fmb = feature_map[b] ([3,HW])
__device__ __forceinline__ void compute_weights(const float* __restrict__ fmb,
                                                int h, int w, int hw,
                                                float* __restrict__ wgt) {
    float c0 = __fadd_rn(fmb[0 * HW + hw], 10.0f);
    float c1 = __fadd_rn(fmb[1 * HW + hw], 10.0f);
    float c2 = __fadd_rn(fmb[2 * HW + hw], 10.0f);
#pragma unroll
    for (int ki = 0; ki < 3; ++ki) {
#pragma unroll
        for (int kj = 0; kj < 3; ++kj) {
            const int k = ki * 3 + kj;
            const int hh = h + ki - 1;
            const int ww2 = w + kj - 1;
            if (hh < 0 || hh >= Hh || ww2 < 0 || ww2 >= Ww) {
                wgt[k] = 0.0f;   // OOB taps contribute exact +0.0
            } else {
                const int nhw = hh * Ww + ww2;
                float d0 = fsub_rn_(__fadd_rn(fmb[0 * HW + nhw], 10.0f), c0);
                float d1 = fsub_rn_(__fadd_rn(fmb[1 * HW + nhw], 10.0f), c1);
                float d2 = fsub_rn_(__fadd_rn(fmb[2 * HW + nhw], 10.0f), c2);
                float ss = __fadd_rn(__fadd_rn(__fmul_rn(d0, d0), __fmul_rn(d1, d1)),
                                     __fmul_rn(d2, d2));
                float color = __fdiv_rn(-ss, 0.5f);                 // /(2*0.5^2)
                const float spk = __fdiv_rn(
                    (float)((ki - 1) * (ki - 1) + (kj - 1) * (kj - 1)), 1800.0f);
                wgt[k] = __fmul_rn(3.0f, expf(fsub_rn_(color, spk)));
            }
        }
    }
}

// Relaxed-only grid barrier: no acquire/release fences (no L2 inv/writeback).
// Shared state travels via agent-scope relaxed atomics (coherent at LLC);
// __syncthreads drains vmcnt(0), so all block stores are at the coherent
// point before the arrival add. Counters monotonic; zeroed per launch.
__device__ __forceinline__ void gbar(int* arrive, int* epoch, int idx,
                                     bool last) {
    __syncthreads();
    if (threadIdx.x == 0)
        __hip_atomic_fetch_add(&arrive[(blockIdx.x & 15) << 4], 1,
                               __ATOMIC_RELAXED, __HIP_MEMORY_SCOPE_AGENT);
    if (blockIdx.x == 0) {
        if (threadIdx.x < 64) {
            const int target = NBLK * (idx + 1);
            for (;;) {
                int v = 0;
                if (threadIdx.x < 16)
                    v = ld_agent_i32(&arrive[threadIdx.x << 4]);
#pragma unroll
                for (int off = 1; off < 64; off <<= 1) v += __shfl_xor(v, off, 64);
                if (v >= target) break;
                __builtin_amdgcn_s_sleep(1);
            }
            if (!last && threadIdx.x < 16)
                __hip_atomic_store(&epoch[threadIdx.x << 4], idx + 1,
                                   __ATOMIC_RELAXED, __HIP_MEMORY_SCOPE_AGENT);
        }
    } else if (!last) {
        if (threadIdx.x == 0) {
            int* ep = &epoch[(blockIdx.x & 15) << 4];
            while (ld_agent_i32(ep) < idx + 1)
                __builtin_amdgcn_s_sleep(2);
        }
    }
    __syncthreads();
}

// state byte: bit0 = (channel0 == 0.55f), bit1 = (channel1 == 0.55f)
__global__ __launch_bounds__(TPB, 4) void fused_kernel(
        const float* __restrict__ x, const float* __restrict__ t,
        const float* __restrict__ fm, float* __restrict__ out,
        int* __restrict__ arrive, int* __restrict__ epoch,
        int* __restrict__ partial,
        unsigned char* __restrict__ st0, unsigned char* __restrict__ st1) {
    const int tid = threadIdx.x;
    const int bid = blockIdx.x;
    const int b = bid / BLKS_PER_B;
    const int rr_ = bid - b * BLKS_PER_B;
    const int ty = rr_ / TX, tx = rr_ - ty * TX;
    const int row0 = ty * TILE_H, col0 = tx * TILE_W;
    const int tr = tid >> 5;              // 0..7
    const int tc = (tid & 31) * 4;        // 0..124
    const int row = row0 + tr, col = col0 + tc;
    const int hw = row * Ww + col;
    const int gp = b * HW + hw;           // gp % 4 == 0

    const float Lg45 = (float)(-log((double)0.45f));
    const float Lg55 = (float)(-log((double)0.55f));

    // ---- once: weights + targets into registers, init state ----
    const float* fmb = fm + (size_t)b * 3 * HW;
    float wall[9][4];
#pragma unroll
    for (int j = 0; j < 4; ++j) {
        float wgt[9];
        compute_weights(fmb, row, col + j, hw + j, wgt);
#pragma unroll
        for (int k = 0; k < 9; ++k) wall[k][j] = wgt[k];
    }
    float4 xv = reinterpret_cast<const float4*>(x)[gp >> 2];
    float4 tv = reinterpret_cast<const float4*>(t)[gp >> 2];
    const float tj[4] = {tv.x, tv.y, tv.z, tv.w};
    {
        unsigned pack =
            ((__fmul_rn(xv.x, tv.x) > 0.5f) ? 2u : 1u) |
            (((__fmul_rn(xv.y, tv.y) > 0.5f) ? 2u : 1u) << 8) |
            (((__fmul_rn(xv.z, tv.z) > 0.5f) ? 2u : 1u) << 16) |
            (((__fmul_rn(xv.w, tv.w) > 0.5f) ? 2u : 1u) << 24);
        st_agent_u32(st0 + gp, pack);
    }

    __shared__ unsigned lds_u[RTOT];
    const unsigned char* lb = (const unsigned char*)lds_u;

    gbar(arrive, epoch, 0, false);

    // ---- 20 iterations ----
    for (int it = 0; it < ITERS; ++it) {
        const bool fin = (it == ITERS - 1);
        const unsigned char* cur = (it & 1) ? st1 : st0;
        unsigned char* nxt = (it & 1) ? st0 : st1;

        // cooperative halo stage: rows row0-1..row0+8, cols col0-4..col0+131
        {
            const unsigned char* base =
                cur + (size_t)b * HW + (row0 - 1) * Ww + (col0 - 4);
            for (int i = tid; i < RTOT; i += TPB) {
                int hr = i / RDW, hc = i - hr * RDW;
                lds_u[i] = ld_agent_u32(base + hr * Ww + hc * 4);
            }
        }
        __syncthreads();

        unsigned opack = 0;
        float o4[4];
#pragma unroll
        for (int j = 0; j < 4; ++j) {
            float a0 = 0.0f, a1 = 0.0f;
#pragma unroll
            for (int ki = 0; ki < 3; ++ki) {
#pragma unroll
                for (int kj = 0; kj < 3; ++kj) {
                    const int k = ki * 3 + kj;
                    // OOB taps: wall==0 -> exact +0.0 regardless of halo bytes
                    unsigned char s = lb[(tr + ki) * RCOLSB + tc + j + 3 + kj];
                    float u0 = (s & 1) ? Lg55 : Lg45;
                    float u1 = (s & 2) ? Lg55 : Lg45;
                    a0 = __fadd_rn(a0, __fmul_rn(u0, wall[k][j]));
                    a1 = __fadd_rn(a1, __fmul_rn(u1, wall[k][j]));
                }
            }
            float f0 = expf(-a0);
            float f1 = __fmul_rn(expf(-a1), tj[j]);
            f0 = __fadd_rn(f0, 1e-6f);
            f1 = __fadd_rn(f1, 1e-6f);
            float S = __fadd_rn(f0, f1);
            float f1n = __fdiv_rn(f1, S);
            if (fin) {
                o4[j] = (f1n > 0.5f) ? 1.0f : 0.0f;
            } else {
                float f0n = __fdiv_rn(f0, S);
                unsigned ns = (f0n > 0.5f ? 1u : 0u) | (f1n > 0.5f ? 2u : 0u);
                opack |= ns << (8 * j);
            }
        }

        if (fin) {
            reinterpret_cast<float4*>(out)[gp >> 2] =
                make_float4(o4[0], o4[1], o4[2], o4[3]);
            int cnt = (o4[0] != 0.0f) + (o4[1] != 0.0f) +
                      (o4[2] != 0.0f) + (o4[3] != 0.0f);
            const int lane = tid & 63;
            const int wv = tid >> 6;
#pragma unroll
            for (int off = 32; off; off >>= 1) cnt += __shfl_down(cnt, off, 64);
            __shared__ int sred[4];
            if (lane == 0) sred[wv] = cnt;
            __syncthreads();
            if (tid == 0) {
                int tot = sred[0] + sred[1] + sred[2] + sred[3];
                __hip_atomic_store(&partial[bid], tot, __ATOMIC_RELAXED,
                                   __HIP_MEMORY_SCOPE_AGENT);
            }
        } else {
            st_agent_u32(nxt + gp, opack);
        }
        gbar(arrive, epoch, it + 1, fin);
    }

    // ---- block 0: reduce partials -> valid ----
    if (bid == 0) {
        const int wv = tid >> 6;          // batch 0..3
        const int lane = tid & 63;
        const int base = wv * BLKS_PER_B; // 144 partials per batch = 64+64+16
        int s = ld_agent_i32(&partial[base + lane]) +
                ld_agent_i32(&partial[base + 64 + lane]);
        if (lane < 16) s += ld_agent_i32(&partial[base + 128 + lane]);
#pragma unroll
        for (int off = 32; off; off >>= 1) s += __shfl_down(s, off, 64);
        if (lane == 0) {
            float cf = (float)s;
            const float lo = (float)(147456.0 * 0.05);
            const float hi = (float)(147456.0 * 0.95);
            out[NPIX + wv] = (cf >= lo && cf <= hi) ? 1.0f : 0.0f;
        }
    }
}

}  // namespace

extern "C" void kernel_launch(void* const* d_in, const int* in_sizes, int n_in,
                              void* d_out, int out_size, void* d_ws, size_t ws_size,
                              hipStream_t stream) {
    const float* x  = (const float*)d_in[0];
    const float* tg = (const float*)d_in[1];
    const float* fm = (const float*)d_in[2];
    float* out = (float*)d_out;

    char* ws = (char*)d_ws;
    // layout: [arrive 16x64B][epoch 16x64B][partial 2304B][st0][st1]
    // end = 4352+pad(256)+2*NPIX < 8192+2*NPIX (proven available in R4)
    int* arrive = (int*)ws;
    int* epoch  = (int*)(ws + 1024);
    int* partial = (int*)(ws + 2048);
    unsigned char* st0 = (unsigned char*)(ws + 4608);
    unsigned char* st1 = st0 + NPIX;

    // zero barrier counters every call (graph-captured, proven in R4)
    (void)hipMemsetAsync(ws, 0, 2048, stream);

    fused_kernel<<<NBLK, TPB, 0, stream>>>(x, tg, fm, out, arrive, epoch,
                                           partial, st0, st1);
}

// Round 6
// 100.898 us; speedup vs baseline: 4.2816x; 1.1890x over previous
//
#include <hip/hip_runtime.h>
#include <math.h>

namespace {

constexpr int Hh = 384;
constexpr int Ww = 384;
constexpr int Bb = 4;
constexpr int HW = Hh * Ww;          // 147456
constexpr int NPIX = Bb * HW;        // 589824
constexpr int ITERS = 20;
constexpr int TPB = 256;

// 2D tiling: each block owns a 128x8 tile (4 px/thread), 3x48 tiles/batch
constexpr int TILE_W = 128;
constexpr int TILE_H = 8;
constexpr int TX = Ww / TILE_W;              // 3
constexpr int TY = Hh / TILE_H;              // 48
constexpr int BLKS_PER_B = TX * TY;          // 144
constexpr int NBLK = Bb * BLKS_PER_B;        // 576

// halo region staged in LDS per iteration: rows row0-1..row0+8, cols col0-4..col0+131
constexpr int RROWS = TILE_H + 2;            // 10
constexpr int RCOLSB = TILE_W + 8;           // 136 bytes
constexpr int RDW = RCOLSB / 4;              // 34 dwords/row
constexpr int RTOT = RROWS * RDW;            // 340 dwords

__device__ __forceinline__ float fsub_rn_(float a, float b) {
    return __fadd_rn(a, -b);
}

__device__ __forceinline__ unsigned ld_agent_u32(const void* p) {
    return __hip_atomic_load((const unsigned*)p, __ATOMIC_RELAXED,
                             __HIP_MEMORY_SCOPE_AGENT);
}
__device__ __forceinline__ void st_agent_u32(void* p, unsigned v) {
    __hip_atomic_store((unsigned*)p, v, __ATOMIC_RELAXED,
                       __HIP_MEMORY_SCOPE_AGENT);
}
__device__ __forceinline__ int ld_agent_i32(const int* p) {
    return __hip_atomic_load(p, __ATOMIC_RELAXED, __HIP_MEMORY_SCOPE_AGENT);
}
__device__ __forceinline__ void st_agent_i32(int* p, int v) {
    __hip_atomic_store(p, v, __ATOMIC_RELAXED, __HIP_MEMORY_SCOPE_AGENT);
}

// 9 pairwise weights for pixel (h,w) of batch-slice fmb = feature_map[b] ([3,HW])
__device__ __forceinline__ void compute_weights(const float* __restrict__ fmb,
                                                int h, int w, int hw,
                                                float* __restrict__ wgt) {
    float c0 = __fadd_rn(fmb[0 * HW + hw], 10.0f);
    float c1 = __fadd_rn(fmb[1 * HW + hw], 10.0f);
    float c2 = __fadd_rn(fmb[2 * HW + hw], 10.0f);
#pragma unroll
    for (int ki = 0; ki < 3; ++ki) {
#pragma unroll
        for (int kj = 0; kj < 3; ++kj) {
            const int k = ki * 3 + kj;
            const int hh = h + ki - 1;
            const int ww2 = w + kj - 1;
            if (hh < 0 || hh >= Hh || ww2 < 0 || ww2 >= Ww) {
                wgt[k] = 0.0f;   // OOB taps contribute exact +0.0
            } else {
                const int nhw = hh * Ww + ww2;
                float d0 = fsub_rn_(__fadd_rn(fmb[0 * HW + nhw], 10.0f), c0);
                float d1 = fsub_rn_(__fadd_rn(fmb[1 * HW + nhw], 10.0f), c1);
                float d2 = fsub_rn_(__fadd_rn(fmb[2 * HW + nhw], 10.0f), c2);
                float ss = __fadd_rn(__fadd_rn(__fmul_rn(d0, d0), __fmul_rn(d1, d1)),
                                     __fmul_rn(d2, d2));
                float color = __fdiv_rn(-ss, 0.5f);                 // /(2*0.5^2)
                const float spk = __fdiv_rn(
                    (float)((ki - 1) * (ki - 1) + (kj - 1) * (kj - 1)), 1800.0f);
                wgt[k] = __fmul_rn(3.0f, expf(fsub_rn_(color, spk)));
            }
        }
    }
}

// state byte: bit0 = (channel0 == 0.55f), bit1 = (channel1 == 0.55f)
// Sync: per-block monotone flags (relaxed agent atomics). flag[bid]=k means
// "this block's state s_k is visible at the coherent point" (guaranteed by
// __syncthreads vmcnt(0) drain before the flag store — proven in R5).
// A block computing iteration i (consuming s_i) waits only on its <=8
// neighbors' flag >= i+1... (flags are 1-based: init state s_0 -> flag 1).
__global__ __launch_bounds__(TPB, 4) void fused_kernel(
        const float* __restrict__ x, const float* __restrict__ t,
        const float* __restrict__ fm, float* __restrict__ out,
        int* __restrict__ arrive, int* __restrict__ flags,
        int* __restrict__ partial,
        unsigned char* __restrict__ st0, unsigned char* __restrict__ st1) {
    const int tid = threadIdx.x;
    const int bid = blockIdx.x;
    const int b = bid / BLKS_PER_B;
    const int rr_ = bid - b * BLKS_PER_B;
    const int ty = rr_ / TX, tx = rr_ - ty * TX;
    const int row0 = ty * TILE_H, col0 = tx * TILE_W;
    const int tr = tid >> 5;              // 0..7
    const int tc = (tid & 31) * 4;        // 0..124
    const int row = row0 + tr, col = col0 + tc;
    const int hw = row * Ww + col;
    const int gp = b * HW + hw;           // gp % 4 == 0

    // per-lane neighbor assignment (lanes 0..7 of wave 0 poll one neighbor each;
    // computed per-thread scalar — no runtime-indexed register array)
    bool nactive = false;
    const int* nflag = nullptr;
    if (tid < 8) {
        const int l2 = (tid < 4) ? tid : tid + 1;       // skip center
        const int dy = l2 / 3 - 1, dx = l2 - (l2 / 3) * 3 - 1;
        const int nty = ty + dy, ntx = tx + dx;
        if (nty >= 0 && nty < TY && ntx >= 0 && ntx < TX) {
            nactive = true;
            nflag = &flags[(b * BLKS_PER_B + nty * TX + ntx) << 4];
        }
    }

    const float Lg45 = (float)(-log((double)0.45f));
    const float Lg55 = (float)(-log((double)0.55f));

    // ---- once: weights + targets into registers, init state ----
    const float* fmb = fm + (size_t)b * 3 * HW;
    float wall[9][4];
#pragma unroll
    for (int j = 0; j < 4; ++j) {
        float wgt[9];
        compute_weights(fmb, row, col + j, hw + j, wgt);
#pragma unroll
        for (int k = 0; k < 9; ++k) wall[k][j] = wgt[k];
    }
    float4 xv = reinterpret_cast<const float4*>(x)[gp >> 2];
    float4 tv = reinterpret_cast<const float4*>(t)[gp >> 2];
    const float tj[4] = {tv.x, tv.y, tv.z, tv.w};
    {
        unsigned pack =
            ((__fmul_rn(xv.x, tv.x) > 0.5f) ? 2u : 1u) |
            (((__fmul_rn(xv.y, tv.y) > 0.5f) ? 2u : 1u) << 8) |
            (((__fmul_rn(xv.z, tv.z) > 0.5f) ? 2u : 1u) << 16) |
            (((__fmul_rn(xv.w, tv.w) > 0.5f) ? 2u : 1u) << 24);
        st_agent_u32(st0 + gp, pack);
    }
    __syncthreads();                      // drain s_0 stores (vmcnt 0)
    if (tid == 0) st_agent_i32(&flags[bid << 4], 1);

    __shared__ unsigned lds_u[RTOT];
    const unsigned char* lb = (const unsigned char*)lds_u;

    // ---- 20 iterations, neighbor-sync only ----
    for (int it = 0; it < ITERS; ++it) {
        const bool fin = (it == ITERS - 1);
        const unsigned char* cur = (it & 1) ? st1 : st0;
        unsigned char* nxt = (it & 1) ? st0 : st1;

        // wait: all neighbors have s_it visible (flag >= it+1)
        if (tid < 64) {
            const int target = it + 1;
            for (;;) {
                bool ok = true;
                if (nactive) ok = (ld_agent_i32(nflag) >= target);
                if (__all(ok)) break;
                __builtin_amdgcn_s_sleep(1);
            }
        }
        __syncthreads();

        // cooperative halo stage: rows row0-1..row0+8, cols col0-4..col0+131
        {
            const unsigned char* base =
                cur + (size_t)b * HW + (row0 - 1) * Ww + (col0 - 4);
            for (int i = tid; i < RTOT; i += TPB) {
                int hr = i / RDW, hc = i - hr * RDW;
                lds_u[i] = ld_agent_u32(base + hr * Ww + hc * 4);
            }
        }
        __syncthreads();

        unsigned opack = 0;
        float o4[4];
#pragma unroll
        for (int j = 0; j < 4; ++j) {
            float a0 = 0.0f, a1 = 0.0f;
#pragma unroll
            for (int ki = 0; ki < 3; ++ki) {
#pragma unroll
                for (int kj = 0; kj < 3; ++kj) {
                    const int k = ki * 3 + kj;
                    // OOB taps: wall==0 -> exact +0.0 regardless of halo bytes
                    unsigned char s = lb[(tr + ki) * RCOLSB + tc + j + 3 + kj];
                    float u0 = (s & 1) ? Lg55 : Lg45;
                    float u1 = (s & 2) ? Lg55 : Lg45;
                    a0 = __fadd_rn(a0, __fmul_rn(u0, wall[k][j]));
                    a1 = __fadd_rn(a1, __fmul_rn(u1, wall[k][j]));
                }
            }
            float f0 = expf(-a0);
            float f1 = __fmul_rn(expf(-a1), tj[j]);
            f0 = __fadd_rn(f0, 1e-6f);
            f1 = __fadd_rn(f1, 1e-6f);
            float S = __fadd_rn(f0, f1);
            float f1n = __fdiv_rn(f1, S);
            if (fin) {
                o4[j] = (f1n > 0.5f) ? 1.0f : 0.0f;
            } else {
                float f0n = __fdiv_rn(f0, S);
                unsigned ns = (f0n > 0.5f ? 1u : 0u) | (f1n > 0.5f ? 2u : 0u);
                opack |= ns << (8 * j);
            }
        }

        if (fin) {
            reinterpret_cast<float4*>(out)[gp >> 2] =
                make_float4(o4[0], o4[1], o4[2], o4[3]);
            int cnt = (o4[0] != 0.0f) + (o4[1] != 0.0f) +
                      (o4[2] != 0.0f) + (o4[3] != 0.0f);
            const int lane = tid & 63;
            const int wv = tid >> 6;
#pragma unroll
            for (int off = 32; off; off >>= 1) cnt += __shfl_down(cnt, off, 64);
            __shared__ int sred[4];
            if (lane == 0) sred[wv] = cnt;
            __syncthreads();
            if (tid == 0) {
                int tot = sred[0] + sred[1] + sred[2] + sred[3];
                st_agent_i32(&partial[bid], tot);
            }
        } else {
            st_agent_u32(nxt + gp, opack);
            __syncthreads();              // drain s_{it+1} stores
            if (tid == 0) st_agent_i32(&flags[bid << 4], it + 2);
        }
    }

    // ---- final global sync (partials), then block 0 reduces -> valid ----
    __syncthreads();                      // drain partial store
    if (tid == 0)
        __hip_atomic_fetch_add(&arrive[(bid & 15) << 4], 1,
                               __ATOMIC_RELAXED, __HIP_MEMORY_SCOPE_AGENT);
    if (bid == 0) {
        if (tid < 64) {
            for (;;) {
                int v = 0;
                if (tid < 16) v = ld_agent_i32(&arrive[tid << 4]);
#pragma unroll
                for (int off = 1; off < 64; off <<= 1) v += __shfl_xor(v, off, 64);
                if (v >= NBLK) break;
                __builtin_amdgcn_s_sleep(1);
            }
        }
        __syncthreads();
        const int wv = tid >> 6;          // batch 0..3
        const int lane = tid & 63;
        const int base = wv * BLKS_PER_B; // 144 partials per batch = 64+64+16
        int s = ld_agent_i32(&partial[base + lane]) +
                ld_agent_i32(&partial[base + 64 + lane]);
        if (lane < 16) s += ld_agent_i32(&partial[base + 128 + lane]);
#pragma unroll
        for (int off = 32; off; off >>= 1) s += __shfl_down(s, off, 64);
        if (lane == 0) {
            float cf = (float)s;
            const float lo = (float)(147456.0 * 0.05);
            const float hi = (float)(147456.0 * 0.95);
            out[NPIX + wv] = (cf >= lo && cf <= hi) ? 1.0f : 0.0f;
        }
    }
}

}  // namespace

extern "C" void kernel_launch(void* const* d_in, const int* in_sizes, int n_in,
                              void* d_out, int out_size, void* d_ws, size_t ws_size,
                              hipStream_t stream) {
    const float* x  = (const float*)d_in[0];
    const float* tg = (const float*)d_in[1];
    const float* fm = (const float*)d_in[2];
    float* out = (float*)d_out;

    char* ws = (char*)d_ws;
    // layout: [arrive 16x64B = 1024][flags 576x64B = 36864][partial 2304]
    //         [pad to 40960][st0][st1]   (ws_size >= 23 MB proven in R2)
    int* arrive  = (int*)ws;
    int* flags   = (int*)(ws + 1024);
    int* partial = (int*)(ws + 1024 + 36864);
    unsigned char* st0 = (unsigned char*)(ws + 40960);
    unsigned char* st1 = st0 + NPIX;

    // zero arrive + flags every call (graph-captured)
    (void)hipMemsetAsync(ws, 0, 1024 + 36864, stream);

    fused_kernel<<<NBLK, TPB, 0, stream>>>(x, tg, fm, out, arrive, flags,
                                           partial, st0, st1);
}

// Round 7
// 88.276 us; speedup vs baseline: 4.8938x; 1.1430x over previous
//
#include <hip/hip_runtime.h>
#include <math.h>

namespace {

constexpr int Hh = 384;
constexpr int Ww = 384;
constexpr int Bb = 4;
constexpr int HW = Hh * Ww;          // 147456
constexpr int NPIX = Bb * HW;        // 589824
constexpr int ITERS = 20;
constexpr int TPB = 256;

// 2D tiling: each block owns a 64x8 tile (2 px/thread), 6x48 tiles/batch
constexpr int TILE_W = 64;
constexpr int TILE_H = 8;
constexpr int TX = Ww / TILE_W;              // 6
constexpr int TY = Hh / TILE_H;              // 48
constexpr int BLKS_PER_B = TX * TY;          // 288
constexpr int NBLK = Bb * BLKS_PER_B;        // 1152  (<= co-residency cap)

// halo staged in LDS per iteration: rows row0-1..row0+8, cols col0-4..col0+67
constexpr int RROWS = TILE_H + 2;            // 10
constexpr int RCOLSB = TILE_W + 8;           // 72 bytes
constexpr int RDW = RCOLSB / 4;              // 18 dwords/row
constexpr int RTOT = RROWS * RDW;            // 180 dwords

__device__ __forceinline__ float fsub_rn_(float a, float b) {
    return __fadd_rn(a, -b);
}

__device__ __forceinline__ unsigned ld_agent_u32(const void* p) {
    return __hip_atomic_load((const unsigned*)p, __ATOMIC_RELAXED,
                             __HIP_MEMORY_SCOPE_AGENT);
}
__device__ __forceinline__ void st_agent_u16(void* p, unsigned short v) {
    __hip_atomic_store((unsigned short*)p, v, __ATOMIC_RELAXED,
                       __HIP_MEMORY_SCOPE_AGENT);
}
__device__ __forceinline__ int ld_agent_i32(const int* p) {
    return __hip_atomic_load(p, __ATOMIC_RELAXED, __HIP_MEMORY_SCOPE_AGENT);
}
__device__ __forceinline__ void st_agent_i32(int* p, int v) {
    __hip_atomic_store(p, v, __ATOMIC_RELAXED, __HIP_MEMORY_SCOPE_AGENT);
}

// 9 pairwise weights for pixel (h,w) of batch-slice fmb = feature_map[b] ([3,HW])
__device__ __forceinline__ void compute_weights(const float* __restrict__ fmb,
                                                int h, int w, int hw,
                                                float* __restrict__ wgt) {
    float c0 = __fadd_rn(fmb[0 * HW + hw], 10.0f);
    float c1 = __fadd_rn(fmb[1 * HW + hw], 10.0f);
    float c2 = __fadd_rn(fmb[2 * HW + hw], 10.0f);
#pragma unroll
    for (int ki = 0; ki < 3; ++ki) {
#pragma unroll
        for (int kj = 0; kj < 3; ++kj) {
            const int k = ki * 3 + kj;
            const int hh = h + ki - 1;
            const int ww2 = w + kj - 1;
            if (hh < 0 || hh >= Hh || ww2 < 0 || ww2 >= Ww) {
                wgt[k] = 0.0f;   // OOB taps contribute exact +0.0
            } else {
                const int nhw = hh * Ww + ww2;
                float d0 = fsub_rn_(__fadd_rn(fmb[0 * HW + nhw], 10.0f), c0);
                float d1 = fsub_rn_(__fadd_rn(fmb[1 * HW + nhw], 10.0f), c1);
                float d2 = fsub_rn_(__fadd_rn(fmb[2 * HW + nhw], 10.0f), c2);
                float ss = __fadd_rn(__fadd_rn(__fmul_rn(d0, d0), __fmul_rn(d1, d1)),
                                     __fmul_rn(d2, d2));
                float color = __fdiv_rn(-ss, 0.5f);                 // /(2*0.5^2)
                const float spk = __fdiv_rn(
                    (float)((ki - 1) * (ki - 1) + (kj - 1) * (kj - 1)), 1800.0f);
                wgt[k] = __fmul_rn(3.0f, expf(fsub_rn_(color, spk)));
            }
        }
    }
}

// state byte: bit0 = (channel0 == 0.55f), bit1 = (channel1 == 0.55f)
// Sync: per-block monotone flags (relaxed agent atomics at LLC; no cache-
// maintenance fences — proven R5/R6). flag[bid]=m <=> s_{m-1} visible.
// A block at loop `it` (consuming s_it) waits on <=8 neighbors' flag >= it+1.
__global__ __launch_bounds__(TPB, 6) void fused_kernel(
        const float* __restrict__ x, const float* __restrict__ t,
        const float* __restrict__ fm, float* __restrict__ out,
        int* __restrict__ arrive, int* __restrict__ flags,
        int* __restrict__ partial,
        unsigned char* __restrict__ st0, unsigned char* __restrict__ st1) {
    const int tid = threadIdx.x;
    const int bid = blockIdx.x;
    const int b = bid / BLKS_PER_B;
    const int rr_ = bid - b * BLKS_PER_B;
    const int ty = rr_ / TX, tx = rr_ - ty * TX;
    const int row0 = ty * TILE_H, col0 = tx * TILE_W;
    const int tr = tid >> 5;              // 0..7
    const int tc = (tid & 31) * 2;        // 0..62
    const int row = row0 + tr, col = col0 + tc;
    const int hw = row * Ww + col;
    const int gp = b * HW + hw;           // gp % 2 == 0

    // lanes 0..7 of wave 0 poll one neighbor each
    bool nactive = false;
    const int* nflag = nullptr;
    if (tid < 8) {
        const int l2 = (tid < 4) ? tid : tid + 1;       // skip center
        const int dy = l2 / 3 - 1, dx = l2 - (l2 / 3) * 3 - 1;
        const int nty = ty + dy, ntx = tx + dx;
        if (nty >= 0 && nty < TY && ntx >= 0 && ntx < TX) {
            nactive = true;
            nflag = &flags[(b * BLKS_PER_B + nty * TX + ntx) << 4];
        }
    }

    const float Lg45 = (float)(-log((double)0.45f));
    const float Lg55 = (float)(-log((double)0.55f));

    // ---- once: weights + targets into registers, init state ----
    const float* fmb = fm + (size_t)b * 3 * HW;
    float wall[9][2];
#pragma unroll
    for (int j = 0; j < 2; ++j) {
        float wgt[9];
        compute_weights(fmb, row, col + j, hw + j, wgt);
#pragma unroll
        for (int k = 0; k < 9; ++k) wall[k][j] = wgt[k];
    }
    float2 xv = reinterpret_cast<const float2*>(x)[gp >> 1];
    float2 tv = reinterpret_cast<const float2*>(t)[gp >> 1];
    const float tj[2] = {tv.x, tv.y};
    {
        unsigned short pack =
            (unsigned short)(((__fmul_rn(xv.x, tv.x) > 0.5f) ? 2u : 1u) |
                             (((__fmul_rn(xv.y, tv.y) > 0.5f) ? 2u : 1u) << 8));
        st_agent_u16(st0 + gp, pack);
    }
    __syncthreads();                      // drain s_0 stores (vmcnt 0)
    if (tid == 0) st_agent_i32(&flags[bid << 4], 1);

    __shared__ unsigned lds_u[RTOT];
    const unsigned char* lb = (const unsigned char*)lds_u;

    // ---- 20 iterations, neighbor-sync only ----
    for (int it = 0; it < ITERS; ++it) {
        const bool fin = (it == ITERS - 1);
        const unsigned char* cur = (it & 1) ? st1 : st0;
        unsigned char* nxt = (it & 1) ? st0 : st1;

        // wait: all neighbors have s_it visible (flag >= it+1)
        if (tid < 64) {
            const int target = it + 1;
            for (;;) {
                bool ok = true;
                if (nactive) ok = (ld_agent_i32(nflag) >= target);
                if (__all(ok)) break;
                __builtin_amdgcn_s_sleep(1);
            }
        }
        __syncthreads();

        // cooperative halo stage: rows row0-1..row0+8, cols col0-4..col0+67
        {
            const unsigned char* base =
                cur + (size_t)b * HW + (row0 - 1) * Ww + (col0 - 4);
            if (tid < RTOT) {
                int hr = tid / RDW, hc = tid - hr * RDW;
                lds_u[tid] = ld_agent_u32(base + hr * Ww + hc * 4);
            }
        }
        __syncthreads();

        unsigned opack = 0;
        float o2[2];
#pragma unroll
        for (int j = 0; j < 2; ++j) {
            float a0 = 0.0f, a1 = 0.0f;
#pragma unroll
            for (int ki = 0; ki < 3; ++ki) {
#pragma unroll
                for (int kj = 0; kj < 3; ++kj) {
                    const int k = ki * 3 + kj;
                    // OOB taps: wall==0 -> exact +0.0 regardless of halo bytes
                    unsigned char s = lb[(tr + ki) * RCOLSB + tc + j + 3 + kj];
                    float u0 = (s & 1) ? Lg55 : Lg45;
                    float u1 = (s & 2) ? Lg55 : Lg45;
                    a0 = __fadd_rn(a0, __fmul_rn(u0, wall[k][j]));
                    a1 = __fadd_rn(a1, __fmul_rn(u1, wall[k][j]));
                }
            }
            float f0 = expf(-a0);
            float f1 = __fmul_rn(expf(-a1), tj[j]);
            f0 = __fadd_rn(f0, 1e-6f);
            f1 = __fadd_rn(f1, 1e-6f);
            float S = __fadd_rn(f0, f1);
            float f1n = __fdiv_rn(f1, S);
            if (fin) {
                o2[j] = (f1n > 0.5f) ? 1.0f : 0.0f;
            } else {
                float f0n = __fdiv_rn(f0, S);
                unsigned ns = (f0n > 0.5f ? 1u : 0u) | (f1n > 0.5f ? 2u : 0u);
                opack |= ns << (8 * j);
            }
        }

        if (fin) {
            reinterpret_cast<float2*>(out)[gp >> 1] = make_float2(o2[0], o2[1]);
            int cnt = (o2[0] != 0.0f) + (o2[1] != 0.0f);
            const int lane = tid & 63;
            const int wv = tid >> 6;
#pragma unroll
            for (int off = 32; off; off >>= 1) cnt += __shfl_down(cnt, off, 64);
            __shared__ int sred[4];
            if (lane == 0) sred[wv] = cnt;
            __syncthreads();
            if (tid == 0) {
                int tot = sred[0] + sred[1] + sred[2] + sred[3];
                st_agent_i32(&partial[bid], tot);
            }
        } else {
            st_agent_u16(nxt + gp, (unsigned short)opack);
            __syncthreads();              // drain s_{it+1} stores
            if (tid == 0) st_agent_i32(&flags[bid << 4], it + 2);
        }
    }

    // ---- final global sync (partials), then block 0 reduces -> valid ----
    __syncthreads();                      // drain partial store
    if (tid == 0)
        __hip_atomic_fetch_add(&arrive[(bid & 15) << 4], 1,
                               __ATOMIC_RELAXED, __HIP_MEMORY_SCOPE_AGENT);
    if (bid == 0) {
        if (tid < 64) {
            for (;;) {
                int v = 0;
                if (tid < 16) v = ld_agent_i32(&arrive[tid << 4]);
#pragma unroll
                for (int off = 1; off < 64; off <<= 1) v += __shfl_xor(v, off, 64);
                if (v >= NBLK) break;
                __builtin_amdgcn_s_sleep(1);
            }
        }
        __syncthreads();
        const int wv = tid >> 6;          // batch 0..3
        const int lane = tid & 63;
        const int base = wv * BLKS_PER_B; // 288 partials per batch = 4x64 + 32
        int s = 0;
#pragma unroll
        for (int k = 0; k < 4; ++k) s += ld_agent_i32(&partial[base + 64 * k + lane]);
        if (lane < 32) s += ld_agent_i32(&partial[base + 256 + lane]);
#pragma unroll
        for (int off = 32; off; off >>= 1) s += __shfl_down(s, off, 64);
        if (lane == 0) {
            float cf = (float)s;
            const float lo = (float)(147456.0 * 0.05);
            const float hi = (float)(147456.0 * 0.95);
            out[NPIX + wv] = (cf >= lo && cf <= hi) ? 1.0f : 0.0f;
        }
    }
}

}  // namespace

extern "C" void kernel_launch(void* const* d_in, const int* in_sizes, int n_in,
                              void* d_out, int out_size, void* d_ws, size_t ws_size,
                              hipStream_t stream) {
    const float* x  = (const float*)d_in[0];
    const float* tg = (const float*)d_in[1];
    const float* fm = (const float*)d_in[2];
    float* out = (float*)d_out;

    char* ws = (char*)d_ws;
    // layout: [arrive 16x64B = 1024][flags 1152x64B = 73728]
    //         [partial 1152x4 = 4608][pad to 79360][st0][st1]
    int* arrive  = (int*)ws;
    int* flags   = (int*)(ws + 1024);
    int* partial = (int*)(ws + 1024 + 73728);
    unsigned char* st0 = (unsigned char*)(ws + 79360);
    unsigned char* st1 = st0 + NPIX;

    // zero arrive + flags every call (graph-captured)
    (void)hipMemsetAsync(ws, 0, 1024 + 73728, stream);

    fused_kernel<<<NBLK, TPB, 0, stream>>>(x, tg, fm, out, arrive, flags,
                                           partial, st0, st1);
}

// Round 8
// 81.830 us; speedup vs baseline: 5.2793x; 1.0788x over previous
//
#include <hip/hip_runtime.h>
#include <math.h>

namespace {

constexpr int Hh = 384;
constexpr int Ww = 384;
constexpr int Bb = 4;
constexpr int HW = Hh * Ww;          // 147456
constexpr int NPIX = Bb * HW;        // 589824
constexpr int ROUNDS = 10;           // 2 mean-field iterations per round
constexpr int TPB = 256;

// 2D tiling: each block owns a 64x8 tile (2 px/thread), 6x48 tiles/batch
constexpr int TILE_W = 64;
constexpr int TILE_H = 8;
constexpr int TX = Ww / TILE_W;              // 6
constexpr int TY = Hh / TILE_H;              // 48
constexpr int BLKS_PER_B = TX * TY;          // 288
constexpr int NBLK = Bb * BLKS_PER_B;        // 1152

// width-2 halo staged per round: rows row0-2..row0+9 (12), col bytes col0-8..col0+71 (80)
constexpr int H2ROWS = 12;
constexpr int H2DW = 20;                     // 80 B / 4
constexpr int H2TOT = H2ROWS * H2DW;         // 240 dwords

// intermediate s_{it+1}: extended region rows row0-1..row0+8 (10) x cols col0-1..col0+64 (66)
constexpr int MIDS = 68;                     // byte stride (10*68 = 680 B)
constexpr int NRING = 148;                   // 2*66 + 2*8 ring pixels

__device__ __forceinline__ float fsub_rn_(float a, float b) {
    return __fadd_rn(a, -b);
}

__device__ __forceinline__ unsigned ld_agent_u32(const void* p) {
    return __hip_atomic_load((const unsigned*)p, __ATOMIC_RELAXED,
                             __HIP_MEMORY_SCOPE_AGENT);
}
__device__ __forceinline__ void st_agent_u16(void* p, unsigned short v) {
    __hip_atomic_store((unsigned short*)p, v, __ATOMIC_RELAXED,
                       __HIP_MEMORY_SCOPE_AGENT);
}
__device__ __forceinline__ int ld_agent_i32(const int* p) {
    return __hip_atomic_load(p, __ATOMIC_RELAXED, __HIP_MEMORY_SCOPE_AGENT);
}
__device__ __forceinline__ void st_agent_i32(int* p, int v) {
    __hip_atomic_store(p, v, __ATOMIC_RELAXED, __HIP_MEMORY_SCOPE_AGENT);
}

// 9 pairwise weights for pixel (h,w) of batch-slice fmb = feature_map[b] ([3,HW])
__device__ __forceinline__ void compute_weights(const float* __restrict__ fmb,
                                                int h, int w, int hw,
                                                float* __restrict__ wgt) {
    float c0 = __fadd_rn(fmb[0 * HW + hw], 10.0f);
    float c1 = __fadd_rn(fmb[1 * HW + hw], 10.0f);
    float c2 = __fadd_rn(fmb[2 * HW + hw], 10.0f);
#pragma unroll
    for (int ki = 0; ki < 3; ++ki) {
#pragma unroll
        for (int kj = 0; kj < 3; ++kj) {
            const int k = ki * 3 + kj;
            const int hh = h + ki - 1;
            const int ww2 = w + kj - 1;
            if (hh < 0 || hh >= Hh || ww2 < 0 || ww2 >= Ww) {
                wgt[k] = 0.0f;   // OOB taps contribute exact +0.0
            } else {
                const int nhw = hh * Ww + ww2;
                float d0 = fsub_rn_(__fadd_rn(fmb[0 * HW + nhw], 10.0f), c0);
                float d1 = fsub_rn_(__fadd_rn(fmb[1 * HW + nhw], 10.0f), c1);
                float d2 = fsub_rn_(__fadd_rn(fmb[2 * HW + nhw], 10.0f), c2);
                float ss = __fadd_rn(__fadd_rn(__fmul_rn(d0, d0), __fmul_rn(d1, d1)),
                                     __fmul_rn(d2, d2));
                float color = __fdiv_rn(-ss, 0.5f);                 // /(2*0.5^2)
                const float spk = __fdiv_rn(
                    (float)((ki - 1) * (ki - 1) + (kj - 1) * (kj - 1)), 1800.0f);
                wgt[k] = __fmul_rn(3.0f, expf(fsub_rn_(color, spk)));
            }
        }
    }
}

// one mean-field pixel update; base points at the top-left (ki=0,kj=0) tap.
// Returns bit0 = (ch0 > 0.5), bit1 = (ch1 > 0.5). FP order identical to ref.
template <int STRIDE>
__device__ __forceinline__ unsigned mf_state(const unsigned char* base,
                                             const float* w9, float tpx,
                                             float Lg45, float Lg55) {
    float a0 = 0.0f, a1 = 0.0f;
#pragma unroll
    for (int ki = 0; ki < 3; ++ki) {
#pragma unroll
        for (int kj = 0; kj < 3; ++kj) {
            const int k = ki * 3 + kj;
            unsigned char s = base[ki * STRIDE + kj];   // garbage when w9[k]==0 -> +0.0
            float u0 = (s & 1) ? Lg55 : Lg45;
            float u1 = (s & 2) ? Lg55 : Lg45;
            a0 = __fadd_rn(a0, __fmul_rn(u0, w9[k]));
            a1 = __fadd_rn(a1, __fmul_rn(u1, w9[k]));
        }
    }
    float f0 = expf(-a0);
    float f1 = __fmul_rn(expf(-a1), tpx);
    f0 = __fadd_rn(f0, 1e-6f);
    f1 = __fadd_rn(f1, 1e-6f);
    float S = __fadd_rn(f0, f1);
    float f0n = __fdiv_rn(f0, S);
    float f1n = __fdiv_rn(f1, S);
    return (f0n > 0.5f ? 1u : 0u) | (f1n > 0.5f ? 2u : 0u);
}

__device__ __forceinline__ void ring_coords(int ri, int& er, int& ec) {
    if (ri < 66)       { er = 0;        ec = ri; }
    else if (ri < 132) { er = 9;        ec = ri - 66; }
    else if (ri < 140) { er = ri - 131; ec = 0; }     // 1..8
    else               { er = ri - 139; ec = 65; }    // 1..8
}

// state byte: bit0 = (channel0 == 0.55f), bit1 = (channel1 == 0.55f)
// Sync: per-block monotone flags (relaxed agent atomics at LLC — proven R5-R7).
// flag[bid] = m  <=>  s_{2(m-1)} visible. Round r consumes s_{2r}: wait
// neighbors' flag >= r+1. Anti-overwrite: flag >= r+1 also implies the
// neighbor finished STAGING s_{2r-2} (start of its round r-1), so the buffer
// we now overwrite is no longer read by anyone.
__global__ __launch_bounds__(TPB, 6) void fused_kernel(
        const float* __restrict__ x, const float* __restrict__ t,
        const float* __restrict__ fm, float* __restrict__ out,
        int* __restrict__ arrive, int* __restrict__ flags,
        int* __restrict__ partial,
        unsigned char* __restrict__ st0, unsigned char* __restrict__ st1) {
    const int tid = threadIdx.x;
    const int bid = blockIdx.x;
    const int b = bid / BLKS_PER_B;
    const int rr_ = bid - b * BLKS_PER_B;
    const int ty = rr_ / TX, tx = rr_ - ty * TX;
    const int row0 = ty * TILE_H, col0 = tx * TILE_W;
    const int tr = tid >> 5;              // 0..7
    const int tc = (tid & 31) * 2;        // 0..62
    const int row = row0 + tr, col = col0 + tc;
    const int hw = row * Ww + col;
    const int gp = b * HW + hw;           // gp % 2 == 0

    // lanes 0..7 of wave 0 poll one neighbor each
    bool nactive = false;
    const int* nflag = nullptr;
    if (tid < 8) {
        const int l2 = (tid < 4) ? tid : tid + 1;       // skip center
        const int dy = l2 / 3 - 1, dx = l2 - (l2 / 3) * 3 - 1;
        const int nty = ty + dy, ntx = tx + dx;
        if (nty >= 0 && nty < TY && ntx >= 0 && ntx < TX) {
            nactive = true;
            nflag = &flags[(b * BLKS_PER_B + nty * TX + ntx) << 4];
        }
    }

    const float Lg45 = (float)(-log((double)0.45f));
    const float Lg55 = (float)(-log((double)0.55f));

    // ---- once: own weights+targets, ring weights+targets, init state ----
    const float* fmb = fm + (size_t)b * 3 * HW;
    float wall[2][9];
#pragma unroll
    for (int j = 0; j < 2; ++j)
        compute_weights(fmb, row, col + j, hw + j, wall[j]);

    bool ringv = false;
    int rer = 0, rec = 0;
    float rw[9] = {0, 0, 0, 0, 0, 0, 0, 0, 0};
    float rt = 0.0f;
    if (tid < NRING) {
        ring_coords(tid, rer, rec);
        const int irow = row0 - 1 + rer, icol = col0 - 1 + rec;
        ringv = (irow >= 0 && irow < Hh && icol >= 0 && icol < Ww);
        if (ringv) {
            compute_weights(fmb, irow, icol, irow * Ww + icol, rw);
            rt = t[(size_t)b * HW + irow * Ww + icol];
        }
    }

    float2 xv = reinterpret_cast<const float2*>(x)[gp >> 1];
    float2 tv = reinterpret_cast<const float2*>(t)[gp >> 1];
    const float tj[2] = {tv.x, tv.y};
    {
        unsigned short pack =
            (unsigned short)(((__fmul_rn(xv.x, tv.x) > 0.5f) ? 2u : 1u) |
                             (((__fmul_rn(xv.y, tv.y) > 0.5f) ? 2u : 1u) << 8));
        st_agent_u16(st0 + gp, pack);
    }
    __syncthreads();                      // drain s_0 stores (vmcnt 0)
    if (tid == 0) st_agent_i32(&flags[bid << 4], 1);

    __shared__ unsigned lds_h2[H2TOT];            // staged s_{2r}, 12x80 B
    __shared__ unsigned char lds_mid[10 * MIDS];  // s_{2r+1}, 10x66 used
    const unsigned char* h2b = (const unsigned char*)lds_h2;

    // ---- 10 rounds x 2 iterations ----
    for (int r = 0; r < ROUNDS; ++r) {
        const bool fin = (r == ROUNDS - 1);
        const unsigned char* cur = (r & 1) ? st1 : st0;
        unsigned char* nxt = (r & 1) ? st0 : st1;

        // wait: all neighbors have s_{2r} visible (flag >= r+1)
        if (tid < 64) {
            const int target = r + 1;
            for (;;) {
                bool ok = true;
                if (nactive) ok = (ld_agent_i32(nflag) >= target);
                if (__all(ok)) break;
                __builtin_amdgcn_s_sleep(1);
            }
        }
        __syncthreads();

        // stage width-2 halo: rows row0-2..row0+9, col bytes col0-8..col0+71
        if (tid < H2TOT) {
            const unsigned char* base2 =
                cur + (size_t)b * HW + (row0 - 2) * Ww + (col0 - 8);
            const int hr = tid / H2DW, hc = tid - hr * H2DW;
            lds_h2[tid] = ld_agent_u32(base2 + hr * Ww + hc * 4);
        }
        __syncthreads();

        // ---- step 1: s_{2r+1} on extended 10x66 region into lds_mid ----
        // interior (own 2 px): extended coords (tr+1, tc+j+1)
#pragma unroll
        for (int j = 0; j < 2; ++j) {
            unsigned m = mf_state<80>(h2b + (tr + 1) * 80 + tc + 7 + j,
                                      wall[j], tj[j], Lg45, Lg55);
            lds_mid[(tr + 1) * MIDS + tc + j + 1] = (unsigned char)m;
        }
        // ring px (threads 0..147, if inside image)
        if (ringv) {
            unsigned m = mf_state<80>(h2b + rer * 80 + rec + 6,
                                      rw, rt, Lg45, Lg55);
            lds_mid[rer * MIDS + rec] = (unsigned char)m;
        }
        __syncthreads();

        // ---- step 2: s_{2r+2} for own 2 px from lds_mid ----
        unsigned n2[2];
#pragma unroll
        for (int j = 0; j < 2; ++j)
            n2[j] = mf_state<MIDS>(lds_mid + tr * MIDS + tc + j,
                                   wall[j], tj[j], Lg45, Lg55);

        if (fin) {
            float o0 = (n2[0] & 2) ? 1.0f : 0.0f;
            float o1 = (n2[1] & 2) ? 1.0f : 0.0f;
            reinterpret_cast<float2*>(out)[gp >> 1] = make_float2(o0, o1);
            int cnt = (o0 != 0.0f) + (o1 != 0.0f);
            const int lane = tid & 63;
            const int wv = tid >> 6;
#pragma unroll
            for (int off = 32; off; off >>= 1) cnt += __shfl_down(cnt, off, 64);
            __shared__ int sred[4];
            if (lane == 0) sred[wv] = cnt;
            __syncthreads();
            if (tid == 0) {
                int tot = sred[0] + sred[1] + sred[2] + sred[3];
                st_agent_i32(&partial[bid], tot);
            }
        } else {
            st_agent_u16(nxt + gp,
                         (unsigned short)(n2[0] | (n2[1] << 8)));
            __syncthreads();              // drain s_{2r+2} stores
            if (tid == 0) st_agent_i32(&flags[bid << 4], r + 2);
        }
    }

    // ---- final global sync (partials), then block 0 reduces -> valid ----
    __syncthreads();                      // drain partial store
    if (tid == 0)
        __hip_atomic_fetch_add(&arrive[(bid & 15) << 4], 1,
                               __ATOMIC_RELAXED, __HIP_MEMORY_SCOPE_AGENT);
    if (bid == 0) {
        if (tid < 64) {
            for (;;) {
                int v = 0;
                if (tid < 16) v = ld_agent_i32(&arrive[tid << 4]);
#pragma unroll
                for (int off = 1; off < 64; off <<= 1) v += __shfl_xor(v, off, 64);
                if (v >= NBLK) break;
                __builtin_amdgcn_s_sleep(1);
            }
        }
        __syncthreads();
        const int wv = tid >> 6;          // batch 0..3
        const int lane = tid & 63;
        const int base = wv * BLKS_PER_B; // 288 partials per batch = 4x64 + 32
        int s = 0;
#pragma unroll
        for (int k = 0; k < 4; ++k) s += ld_agent_i32(&partial[base + 64 * k + lane]);
        if (lane < 32) s += ld_agent_i32(&partial[base + 256 + lane]);
#pragma unroll
        for (int off = 32; off; off >>= 1) s += __shfl_down(s, off, 64);
        if (lane == 0) {
            float cf = (float)s;
            const float lo = (float)(147456.0 * 0.05);
            const float hi = (float)(147456.0 * 0.95);
            out[NPIX + wv] = (cf >= lo && cf <= hi) ? 1.0f : 0.0f;
        }
    }
}

}  // namespace

extern "C" void kernel_launch(void* const* d_in, const int* in_sizes, int n_in,
                              void* d_out, int out_size, void* d_ws, size_t ws_size,
                              hipStream_t stream) {
    const float* x  = (const float*)d_in[0];
    const float* tg = (const float*)d_in[1];
    const float* fm = (const float*)d_in[2];
    float* out = (float*)d_out;

    char* ws = (char*)d_ws;
    // layout: [arrive 16x64B = 1024][flags 1152x64B = 73728]
    //         [partial 1152x4 = 4608][pad to 79360][st0][st1]
    int* arrive  = (int*)ws;
    int* flags   = (int*)(ws + 1024);
    int* partial = (int*)(ws + 1024 + 73728);
    unsigned char* st0 = (unsigned char*)(ws + 79360);
    unsigned char* st1 = st0 + NPIX;

    // zero arrive + flags every call (graph-captured)
    (void)hipMemsetAsync(ws, 0, 1024 + 73728, stream);

    fused_kernel<<<NBLK, TPB, 0, stream>>>(x, tg, fm, out, arrive, flags,
                                           partial, st0, st1);
}